// Round 3
// baseline (3923.241 us; speedup 1.0000x reference)
//
#include <hip/hip_runtime.h>
#include <math.h>

// Problem constants
constexpr int kT = 2048;   // tokens (B*S)
constexpr int kH = 1024;   // hidden
constexpr int kI = 4096;   // ffn inner
constexpr int kE = 8;      // experts
constexpr int kV = 32000;  // vocab
constexpr int kL = 2;      // layers

typedef __attribute__((ext_vector_type(4))) float f32x4;
typedef __attribute__((ext_vector_type(8))) short bf16x8;

// f32 pair -> packed bf16x2 (gfx950 v_cvt_pk_bf16_f32; T12 recipe)
__device__ inline unsigned cvtpk(float lo, float hi) {
  unsigned r;
  asm("v_cvt_pk_bf16_f32 %0, %1, %2" : "=v"(r) : "v"(lo), "v"(hi));
  return r;
}

// ---------------- small per-token kernels ----------------

__global__ void gather_k(const int* __restrict__ ids, const float* __restrict__ emb,
                         float* __restrict__ h) {
  int t = blockIdx.x;
  int id = ids[t];
  const float4* src = (const float4*)(emb + (size_t)id * kH);
  float4* dst = (float4*)(h + (size_t)t * kH);
  dst[threadIdx.x] = src[threadIdx.x];
}

__global__ void router_k(const float* __restrict__ h, const float* __restrict__ rw,
                         const float* __restrict__ rb, float* __restrict__ logits) {
  int t = blockIdx.x;
  int lg = threadIdx.x & 31;
  int e = threadIdx.x >> 5;
  const float* hr = h + (size_t)t * kH;
  const float* wr = rw + (size_t)e * kH;
  float p = 0.f;
  for (int k = lg * 4; k < kH; k += 128) {
    float4 a = *(const float4*)(hr + k);
    float4 b = *(const float4*)(wr + k);
    p += a.x * b.x + a.y * b.y + a.z * b.z + a.w * b.w;
  }
  for (int o = 16; o > 0; o >>= 1) p += __shfl_down(p, o, 32);
  if (lg == 0) logits[t * kE + e] = p + rb[e];
}

__global__ void topk_k(const float* __restrict__ logits, int* __restrict__ sel,
                       float* __restrict__ w_sum, int* __restrict__ cnt) {
  int t = blockIdx.x * blockDim.x + threadIdx.x;
  if (t >= kT) return;
  float v[8];
#pragma unroll
  for (int e = 0; e < 8; e++) v[e] = logits[t * 8 + e];
  int e1 = 0; float v1 = v[0];
#pragma unroll
  for (int e = 1; e < 8; e++) if (v[e] > v1) { v1 = v[e]; e1 = e; }
  int e2 = -1; float v2 = -3.4e38f;
#pragma unroll
  for (int e = 0; e < 8; e++) if (e != e1 && v[e] > v2) { v2 = v[e]; e2 = e; }
  float z = expf(v2 - v1);
  float w1 = 1.f / (1.f + z);
  float w2 = z * w1;
  sel[t * 2] = e1;
  sel[t * 2 + 1] = e2;
  atomicAdd(&w_sum[e1], w1);
  atomicAdd(&w_sum[e2], w2);
  atomicAdd(&cnt[e1], 1);
  atomicAdd(&cnt[e2], 1);
}

__global__ void finalize_k(const int* __restrict__ cnt, const float* __restrict__ w_sum,
                           float* __restrict__ scal, int* __restrict__ off,
                           int* __restrict__ fill, float* __restrict__ aux) {
  if (threadIdx.x == 0) {
    int o = 0;
    float a = 0.f;
    for (int e = 0; e < 8; e++) {
      off[e] = o;
      o += cnt[e];
      fill[e] = 0;
      int c = cnt[e];
      scal[e] = c > 0 ? w_sum[e] / (float)c : 0.f;
      float d = (float)c - 256.f;
      a += d * d;
    }
    aux[0] += 0.01f * (a * 0.125f);
  }
}

__global__ void scatter_k(const int* __restrict__ sel, const int* __restrict__ off,
                          int* __restrict__ fill, int* __restrict__ list) {
  int t = blockIdx.x * blockDim.x + threadIdx.x;
  if (t >= kT) return;
#pragma unroll
  for (int s = 0; s < 2; s++) {
    int e = sel[t * 2 + s];
    int p = atomicAdd(&fill[e], 1);
    list[off[e] + p] = t;
  }
}

__global__ void ln_k(float* __restrict__ h, const float* __restrict__ x,
                     const float* __restrict__ g, const float* __restrict__ b) {
  int t = blockIdx.x;
  const float* xr = x + (size_t)t * kH;
  int k = threadIdx.x * 4;
  float4 v = *(const float4*)(xr + k);
  float s = v.x + v.y + v.z + v.w;
  float sq = v.x * v.x + v.y * v.y + v.z * v.z + v.w * v.w;
  for (int o = 32; o > 0; o >>= 1) {
    s += __shfl_down(s, o);
    sq += __shfl_down(sq, o);
  }
  __shared__ float ss[4], sqs[4];
  int wave = threadIdx.x >> 6, lane = threadIdx.x & 63;
  if (lane == 0) { ss[wave] = s; sqs[wave] = sq; }
  __syncthreads();
  __shared__ float mu, inv;
  if (threadIdx.x == 0) {
    float st = ss[0] + ss[1] + ss[2] + ss[3];
    float sqt = sqs[0] + sqs[1] + sqs[2] + sqs[3];
    float m = st / (float)kH;
    float var = sqt / (float)kH - m * m;
    mu = m;
    inv = 1.f / sqrtf(var + 1e-5f);
  }
  __syncthreads();
  float4 gg = *(const float4*)(g + k);
  float4 bb = *(const float4*)(b + k);
  float4 o;
  o.x = (v.x - mu) * inv * gg.x + bb.x;
  o.y = (v.y - mu) * inv * gg.y + bb.y;
  o.z = (v.z - mu) * inv * gg.z + bb.z;
  o.w = (v.w - mu) * inv * gg.w + bb.w;
  *(float4*)(h + (size_t)t * kH + k) = o;
}

__global__ void aux_write_k(float* __restrict__ out, const float* __restrict__ aux) {
  out[(size_t)kT * kV] = aux[0];
}

// ---------------- f32 tiled GEMM (layer-1 FFN: routing-critical, exact) ----------------
// MODE 0: fc1 (gather rows, GELU -> f32 a_buf)
// MODE 1: fc2 (compact rows, split-K=4, scal*(acc+bias) atomicAdd scatter)
template <int MODE>
__launch_bounds__(256)
__global__ void gemm_k(const float* __restrict__ Abase, int ldA,
                       const float* __restrict__ Bbase,
                       const float* __restrict__ bias,
                       float* __restrict__ Cout,
                       const int* __restrict__ list,
                       const int* __restrict__ off,
                       const int* __restrict__ cnt,
                       const float* __restrict__ scal,
                       int N, int Kd) {
  const int e = blockIdx.z;
  int M = cnt[e];
  const int m0 = blockIdx.x * 128;
  if (m0 >= M) return;
  int nb = blockIdx.y, kc = 0;
  if constexpr (MODE == 1) { nb = blockIdx.y >> 2; kc = blockIdx.y & 3; }
  const int n0 = nb * 128;
  int roff = off[e];
  const float* Bp = Bbase + (size_t)e * (size_t)N * (size_t)Kd;
  const float* be = bias + (size_t)e * (size_t)N;
  const int kBeg = (MODE == 1) ? kc * (Kd >> 2) : 0;
  const int kEnd = (MODE == 1) ? kBeg + (Kd >> 2) : Kd;

  __shared__ float As[16][132];
  __shared__ float Bs[16][132];

  const int tid = threadIdx.x;
  const float* aptr[2];
  const float* bptr[2];
#pragma unroll
  for (int q = 0; q < 2; q++) {
    int s = tid + q * 256;
    int row = s >> 2, kq = (s & 3) * 4;
    int r = m0 + row;
    int rc = r < M ? r : M - 1;
    size_t asrc;
    if constexpr (MODE == 0) asrc = (size_t)list[roff + rc] * (size_t)ldA;
    else asrc = (size_t)(roff + rc) * (size_t)ldA;
    aptr[q] = Abase + asrc + kq;
    bptr[q] = Bp + (size_t)(n0 + row) * (size_t)Kd + kq;
  }

  float acc[8][8] = {};
  const int tx = tid & 15, ty = tid >> 4;

  for (int k0 = kBeg; k0 < kEnd; k0 += 16) {
#pragma unroll
    for (int q = 0; q < 2; q++) {
      int s = tid + q * 256;
      int row = s >> 2, kq = (s & 3) * 4;
      float4 va = *(const float4*)(aptr[q] + k0);
      float4 vb = *(const float4*)(bptr[q] + k0);
      As[kq + 0][row] = va.x; As[kq + 1][row] = va.y;
      As[kq + 2][row] = va.z; As[kq + 3][row] = va.w;
      Bs[kq + 0][row] = vb.x; Bs[kq + 1][row] = vb.y;
      Bs[kq + 2][row] = vb.z; Bs[kq + 3][row] = vb.w;
    }
    __syncthreads();
#pragma unroll
    for (int k = 0; k < 16; k++) {
      float a[8], b[8];
      *(float4*)&a[0] = *(const float4*)&As[k][ty * 8];
      *(float4*)&a[4] = *(const float4*)&As[k][ty * 8 + 4];
      *(float4*)&b[0] = *(const float4*)&Bs[k][tx * 8];
      *(float4*)&b[4] = *(const float4*)&Bs[k][tx * 8 + 4];
#pragma unroll
      for (int i = 0; i < 8; i++)
#pragma unroll
        for (int j = 0; j < 8; j++)
          acc[i][j] = fmaf(a[i], b[j], acc[i][j]);
    }
    __syncthreads();
  }

#pragma unroll
  for (int i = 0; i < 8; i++) {
    int gm = m0 + ty * 8 + i;
    if (gm >= M) continue;
    if constexpr (MODE == 0) {
      float* orow = Cout + (size_t)(roff + gm) * (size_t)N + n0 + tx * 8;
#pragma unroll
      for (int j = 0; j < 8; j++) {
        float x = acc[i][j] + be[n0 + tx * 8 + j];
        orow[j] = 0.5f * x * (1.f + erff(x * 0.70710678118654752f));
      }
    } else {
      int t = list[roff + gm];
      float se = scal[e];
      float* orow = Cout + (size_t)t * (size_t)N + n0 + tx * 8;
#pragma unroll
      for (int j = 0; j < 8; j++) {
        float bb = (kc == 0) ? be[n0 + tx * 8 + j] : 0.f;
        atomicAdd(&orow[j], se * (acc[i][j] + bb));
      }
    }
  }
}

// ---------------- bf16 MFMA GEMM with in-register f32->bf16 staging ----------------
// 128x128 tile, BK=64, 256 threads = 4 waves (2x2), 16x16x32 bf16 MFMA.
// f32 operands: global float4 loads -> v_cvt_pk_bf16_f32 -> ds_write_b128,
// linear LDS [128][64] bf16 (same layout as the verified global_load_lds version).
// Next K-tile's loads issue right after the first barrier (hide HBM under MFMA).
// MODE 0: fc1-l2 (A rows via list gather, GELU -> f32 a_buf)
// MODE 1: fc2-l2 (A = compact a_buf, split-K=4, scal*(acc+bias) atomicAdd scatter)
// MODE 2: head  (dense, +bias -> f32 out)
template <int MODE>
__launch_bounds__(256)
__global__ void mgemm_k(const float* __restrict__ Abase, int ldA,
                        const float* __restrict__ Bbase,
                        const float* __restrict__ bias,
                        float* __restrict__ Cout,
                        const int* __restrict__ list,
                        const int* __restrict__ off,
                        const int* __restrict__ cnt,
                        const float* __restrict__ scal,
                        int N, int Kd) {
  const int e = (MODE == 2) ? 0 : blockIdx.z;
  int M;
  if constexpr (MODE == 2) M = kT; else M = cnt[e];
  const int m0 = blockIdx.x * 128;
  if (m0 >= M) return;
  int nb = blockIdx.y, kc = 0;
  if constexpr (MODE == 1) { nb = blockIdx.y >> 2; kc = blockIdx.y & 3; }
  const int n0 = nb * 128;
  int roff = 0;
  if constexpr (MODE != 2) roff = off[e];
  const float* Bp = Bbase + (size_t)e * (size_t)N * (size_t)Kd;
  const float* be = bias + (size_t)e * (size_t)N;
  const int kBeg = (MODE == 1) ? kc * (Kd >> 2) : 0;
  const int kEnd = (MODE == 1) ? kBeg + (Kd >> 2) : Kd;

  __shared__ unsigned short As[128 * 64];
  __shared__ unsigned short Bs[128 * 64];

  const int tid = threadIdx.x, w = tid >> 6, l = tid & 63;

  // staging: lane covers, for chunk i in 0..3: row r = w*8 + i*32 + (l>>3),
  // col (l&7)*8 .. +8 (8 f32 -> 8 bf16 = one ds_write_b128). Consecutive lanes
  // hit consecutive 16B LDS slots -> conflict-free writes.
  const float* asrc[4];
  const float* bsrc[4];
#pragma unroll
  for (int i = 0; i < 4; i++) {
    int r = w * 8 + i * 32 + (l >> 3);
    int gr = m0 + r; if (gr > M - 1) gr = M - 1;
    long grow;
    if constexpr (MODE == 0) grow = list[roff + gr];
    else if constexpr (MODE == 1) grow = roff + gr;
    else grow = gr;
    asrc[i] = Abase + grow * (long)ldA + (l & 7) * 8;
    bsrc[i] = Bp + (size_t)(n0 + r) * (size_t)Kd + (l & 7) * 8;
  }
  const int ldst = w * 512 + (l >> 3) * 64 + (l & 7) * 8;  // bf16-elem offset

  f32x4 acc[4][4] = {};
  const int wm = w >> 1, wn = w & 1;
  const int fr = l & 15, fk = (l >> 4) * 8;

  float4 ra[4][2], rb[4][2];

#define LOAD_TILE(K0)                                        \
  _Pragma("unroll") for (int i = 0; i < 4; i++) {            \
    ra[i][0] = *(const float4*)(asrc[i] + (K0));             \
    ra[i][1] = *(const float4*)(asrc[i] + (K0) + 4);         \
    rb[i][0] = *(const float4*)(bsrc[i] + (K0));             \
    rb[i][1] = *(const float4*)(bsrc[i] + (K0) + 4);         \
  }

  LOAD_TILE(kBeg);

  for (int k0 = kBeg; k0 < kEnd; k0 += 64) {
    // cvt + LDS write of the tile loaded last iteration
#pragma unroll
    for (int i = 0; i < 4; i++) {
      uint4 pa, pb;
      pa.x = cvtpk(ra[i][0].x, ra[i][0].y);
      pa.y = cvtpk(ra[i][0].z, ra[i][0].w);
      pa.z = cvtpk(ra[i][1].x, ra[i][1].y);
      pa.w = cvtpk(ra[i][1].z, ra[i][1].w);
      pb.x = cvtpk(rb[i][0].x, rb[i][0].y);
      pb.y = cvtpk(rb[i][0].z, rb[i][0].w);
      pb.z = cvtpk(rb[i][1].x, rb[i][1].y);
      pb.w = cvtpk(rb[i][1].z, rb[i][1].w);
      *(uint4*)(As + ldst + i * 2048) = pa;
      *(uint4*)(Bs + ldst + i * 2048) = pb;
    }
    __syncthreads();
    if (k0 + 64 < kEnd) LOAD_TILE(k0 + 64);  // prefetch; latency hides under MFMA
#pragma unroll
    for (int ks = 0; ks < 2; ks++) {
      bf16x8 af[4], bfr[4];
#pragma unroll
      for (int am = 0; am < 4; am++)
        af[am] = *(const bf16x8*)(As + (wm * 64 + am * 16 + fr) * 64 + ks * 32 + fk);
#pragma unroll
      for (int bn = 0; bn < 4; bn++)
        bfr[bn] = *(const bf16x8*)(Bs + (wn * 64 + bn * 16 + fr) * 64 + ks * 32 + fk);
#pragma unroll
      for (int am = 0; am < 4; am++)
#pragma unroll
        for (int bn = 0; bn < 4; bn++)
          acc[am][bn] = __builtin_amdgcn_mfma_f32_16x16x32_bf16(af[am], bfr[bn], acc[am][bn], 0, 0, 0);
    }
    __syncthreads();
  }
#undef LOAD_TILE

  // C/D layout: col = lane&15, row = (lane>>4)*4 + j  (m89/m91-verified)
  const int r0 = (l >> 4) * 4, cc = l & 15;
#pragma unroll
  for (int am = 0; am < 4; am++) {
#pragma unroll
    for (int bn = 0; bn < 4; bn++) {
      int gn = n0 + wn * 64 + bn * 16 + cc;
      float bv;
      if constexpr (MODE == 1) bv = (kc == 0) ? be[gn] : 0.f;
      else bv = be[gn];
#pragma unroll
      for (int j = 0; j < 4; j++) {
        int gm = m0 + wm * 64 + am * 16 + r0 + j;
        if (gm >= M) continue;
        float v = acc[am][bn][j] + bv;
        if constexpr (MODE == 0) {
          float g = 0.5f * v * (1.f + erff(v * 0.70710678118654752f));
          Cout[(size_t)(roff + gm) * (size_t)N + gn] = g;
        } else if constexpr (MODE == 1) {
          int t = list[roff + gm];
          atomicAdd(&Cout[(size_t)t * (size_t)N + gn], scal[e] * v);
        } else {
          Cout[(size_t)gm * (size_t)N + gn] = v;
        }
      }
    }
  }
}

// ---------------- launch ----------------

extern "C" void kernel_launch(void* const* d_in, const int* in_sizes, int n_in,
                              void* d_out, int out_size, void* d_ws, size_t ws_size,
                              hipStream_t stream) {
  (void)in_sizes; (void)n_in; (void)out_size; (void)ws_size;
  const int* ids = (const int*)d_in[0];
  const float* emb = (const float*)d_in[1];
  const float* router_w = (const float*)d_in[2];
  const float* router_b = (const float*)d_in[3];
  const float* fc1_w = (const float*)d_in[4];
  const float* fc1_b = (const float*)d_in[5];
  const float* fc2_w = (const float*)d_in[6];
  const float* fc2_b = (const float*)d_in[7];
  const float* ln_g = (const float*)d_in[8];
  const float* ln_b = (const float*)d_in[9];
  const float* head_w = (const float*)d_in[10];
  const float* head_b = (const float*)d_in[11];
  float* out = (float*)d_out;

  // --- workspace layout (~17 MB) ---
  float* ws_f = (float*)d_ws;
  float* h       = ws_f;                          // kT*kH
  float* out_acc = h + (size_t)kT * kH;           // kT*kH
  float* logits  = out_acc + (size_t)kT * kH;     // kT*kE
  float* w_sum   = logits + (size_t)kT * kE;      // kE
  float* scal    = w_sum + kE;                    // kE
  float* aux     = scal + kE;                     // 1
  int* sel  = (int*)(aux + 1);                    // kT*2
  int* cnt  = sel + 2 * kT;                       // kE
  int* off  = cnt + kE;                           // kE
  int* fill = off + kE;                           // kE
  int* list = fill + kE;                          // kT*2

  // fc1 activation buffer (4096 x kI f32 = 64 MB) in d_out; head overwrites it.
  float* a_f32 = out;

  hipMemsetAsync(aux, 0, sizeof(float), stream);
  gather_k<<<kT, 256, 0, stream>>>(ids, emb, h);

  for (int l = 0; l < kL; l++) {
    hipMemsetAsync(w_sum, 0, kE * sizeof(float), stream);
    hipMemsetAsync(cnt, 0, kE * sizeof(int), stream);
    router_k<<<kT, 256, 0, stream>>>(h, router_w + (size_t)l * kE * kH,
                                     router_b + (size_t)l * kE, logits);
    topk_k<<<kT / 256, 256, 0, stream>>>(logits, sel, w_sum, cnt);
    finalize_k<<<1, 64, 0, stream>>>(cnt, w_sum, scal, off, fill, aux);
    scatter_k<<<kT / 256, 256, 0, stream>>>(sel, off, fill, list);
    hipMemsetAsync(out_acc, 0, (size_t)kT * kH * sizeof(float), stream);

    if (l == 0) {
      // layer-1: exact f32 (its output feeds the layer-2 router)
      gemm_k<0><<<dim3(kT / 128, kI / 128, kE), 256, 0, stream>>>(
          h, kH, fc1_w + (size_t)l * kE * kI * kH, fc1_b + (size_t)l * kE * kI,
          a_f32, list, off, cnt, scal, kI, kH);
      gemm_k<1><<<dim3(kT / 128, (kH / 128) * 4, kE), 256, 0, stream>>>(
          a_f32, kI, fc2_w + (size_t)l * kE * kH * kI, fc2_b + (size_t)l * kE * kH,
          out_acc, list, off, cnt, scal, kH, kI);
    } else {
      // layer-2: bf16 MFMA, f32 operands converted during staging
      mgemm_k<0><<<dim3(kT / 128, kI / 128, kE), 256, 0, stream>>>(
          h, kH, fc1_w + (size_t)l * kE * kI * kH, fc1_b + (size_t)l * kE * kI,
          a_f32, list, off, cnt, scal, kI, kH);
      mgemm_k<1><<<dim3(kT / 128, (kH / 128) * 4, kE), 256, 0, stream>>>(
          a_f32, kI, fc2_w + (size_t)l * kE * kH * kI, fc2_b + (size_t)l * kE * kH,
          out_acc, list, off, cnt, scal, kH, kI);
    }

    ln_k<<<kT, 256, 0, stream>>>(h, out_acc, ln_g + (size_t)l * kH, ln_b + (size_t)l * kH);
  }

  // head: bf16 MFMA with f32 staging; reads h (ws) + head_w (input), writes all of d_out
  mgemm_k<2><<<dim3(kT / 128, kV / 128, 1), 256, 0, stream>>>(
      h, kH, head_w, head_b, out, nullptr, nullptr, nullptr, nullptr, kV, kH);

  aux_write_k<<<1, 1, 0, stream>>>(out, aux);
}

// Round 4
// 3722.808 us; speedup vs baseline: 1.0538x; 1.0538x over previous
//
#include <hip/hip_runtime.h>
#include <math.h>

// Problem constants
constexpr int kT = 2048;   // tokens (B*S)
constexpr int kH = 1024;   // hidden
constexpr int kI = 4096;   // ffn inner
constexpr int kE = 8;      // experts
constexpr int kV = 32000;  // vocab
constexpr int kL = 2;      // layers
constexpr int kR = 4096;   // total routed rows = K*T
constexpr int kSK = 4;     // fc2 split-K chunks

typedef __attribute__((ext_vector_type(4))) float f32x4;
typedef __attribute__((ext_vector_type(8))) short bf16x8;

// f32 pair -> packed bf16x2 (gfx950 v_cvt_pk_bf16_f32; T12 recipe)
__device__ inline unsigned cvtpk(float lo, float hi) {
  unsigned r;
  asm("v_cvt_pk_bf16_f32 %0, %1, %2" : "=v"(r) : "v"(lo), "v"(hi));
  return r;
}

// ---------------- small per-token kernels ----------------

__global__ void gather_k(const int* __restrict__ ids, const float* __restrict__ emb,
                         float* __restrict__ h) {
  int t = blockIdx.x;
  int id = ids[t];
  const float4* src = (const float4*)(emb + (size_t)id * kH);
  float4* dst = (float4*)(h + (size_t)t * kH);
  dst[threadIdx.x] = src[threadIdx.x];
}

__global__ void router_k(const float* __restrict__ h, const float* __restrict__ rw,
                         const float* __restrict__ rb, float* __restrict__ logits) {
  int t = blockIdx.x;
  int lg = threadIdx.x & 31;
  int e = threadIdx.x >> 5;
  const float* hr = h + (size_t)t * kH;
  const float* wr = rw + (size_t)e * kH;
  float p = 0.f;
  for (int k = lg * 4; k < kH; k += 128) {
    float4 a = *(const float4*)(hr + k);
    float4 b = *(const float4*)(wr + k);
    p += a.x * b.x + a.y * b.y + a.z * b.z + a.w * b.w;
  }
  for (int o = 16; o > 0; o >>= 1) p += __shfl_down(p, o, 32);
  if (lg == 0) logits[t * kE + e] = p + rb[e];
}

__global__ void topk_k(const float* __restrict__ logits, int* __restrict__ sel,
                       float* __restrict__ w_sum, int* __restrict__ cnt) {
  int t = blockIdx.x * blockDim.x + threadIdx.x;
  if (t >= kT) return;
  float v[8];
#pragma unroll
  for (int e = 0; e < 8; e++) v[e] = logits[t * 8 + e];
  int e1 = 0; float v1 = v[0];
#pragma unroll
  for (int e = 1; e < 8; e++) if (v[e] > v1) { v1 = v[e]; e1 = e; }
  int e2 = -1; float v2 = -3.4e38f;
#pragma unroll
  for (int e = 0; e < 8; e++) if (e != e1 && v[e] > v2) { v2 = v[e]; e2 = e; }
  float z = expf(v2 - v1);
  float w1 = 1.f / (1.f + z);
  float w2 = z * w1;
  sel[t * 2] = e1;
  sel[t * 2 + 1] = e2;
  atomicAdd(&w_sum[e1], w1);
  atomicAdd(&w_sum[e2], w2);
  atomicAdd(&cnt[e1], 1);
  atomicAdd(&cnt[e2], 1);
}

__global__ void finalize_k(const int* __restrict__ cnt, const float* __restrict__ w_sum,
                           float* __restrict__ scal, int* __restrict__ off,
                           int* __restrict__ fill, float* __restrict__ aux) {
  if (threadIdx.x == 0) {
    int o = 0;
    float a = 0.f;
    for (int e = 0; e < 8; e++) {
      off[e] = o;
      o += cnt[e];
      fill[e] = 0;
      int c = cnt[e];
      scal[e] = c > 0 ? w_sum[e] / (float)c : 0.f;
      float d = (float)c - 256.f;
      a += d * d;
    }
    aux[0] += 0.01f * (a * 0.125f);
  }
}

// records each token's compact-slot position for the combine step
__global__ void scatter_k(const int* __restrict__ sel, const int* __restrict__ off,
                          int* __restrict__ fill, int* __restrict__ list,
                          int* __restrict__ pos) {
  int t = blockIdx.x * blockDim.x + threadIdx.x;
  if (t >= kT) return;
#pragma unroll
  for (int s = 0; s < 2; s++) {
    int e = sel[t * 2 + s];
    int p = atomicAdd(&fill[e], 1);
    int slot = off[e] + p;
    list[slot] = t;
    pos[t * 2 + s] = slot;
  }
}

// out[t] = LayerNorm( sum_{s in 2} sum_{kc in 4} c_comp[kc][pos[t,s]] ) -> h
__global__ void combine_ln_k(const float* __restrict__ ccomp, const int* __restrict__ pos,
                             float* __restrict__ h, const float* __restrict__ g,
                             const float* __restrict__ b) {
  int t = blockIdx.x;
  int s0 = pos[t * 2], s1 = pos[t * 2 + 1];
  int k = threadIdx.x * 4;
  float4 v = {0.f, 0.f, 0.f, 0.f};
#pragma unroll
  for (int kc = 0; kc < kSK; kc++) {
    const float* base = ccomp + (size_t)kc * ((size_t)kR * kH);
    float4 a = *(const float4*)(base + (size_t)s0 * kH + k);
    float4 c = *(const float4*)(base + (size_t)s1 * kH + k);
    v.x += a.x + c.x; v.y += a.y + c.y; v.z += a.z + c.z; v.w += a.w + c.w;
  }
  float s = v.x + v.y + v.z + v.w;
  float sq = v.x * v.x + v.y * v.y + v.z * v.z + v.w * v.w;
  for (int o = 32; o > 0; o >>= 1) {
    s += __shfl_down(s, o);
    sq += __shfl_down(sq, o);
  }
  __shared__ float ss[4], sqs[4];
  int wave = threadIdx.x >> 6, lane = threadIdx.x & 63;
  if (lane == 0) { ss[wave] = s; sqs[wave] = sq; }
  __syncthreads();
  __shared__ float mu, inv;
  if (threadIdx.x == 0) {
    float st = ss[0] + ss[1] + ss[2] + ss[3];
    float sqt = sqs[0] + sqs[1] + sqs[2] + sqs[3];
    float m = st / (float)kH;
    float var = sqt / (float)kH - m * m;
    mu = m;
    inv = 1.f / sqrtf(var + 1e-5f);
  }
  __syncthreads();
  float4 gg = *(const float4*)(g + k);
  float4 bb = *(const float4*)(b + k);
  float4 o;
  o.x = (v.x - mu) * inv * gg.x + bb.x;
  o.y = (v.y - mu) * inv * gg.y + bb.y;
  o.z = (v.z - mu) * inv * gg.z + bb.z;
  o.w = (v.w - mu) * inv * gg.w + bb.w;
  *(float4*)(h + (size_t)t * kH + k) = o;
}

__global__ void aux_write_k(float* __restrict__ out, const float* __restrict__ aux) {
  out[(size_t)kT * kV] = aux[0];
}

// ---------------- f32 tiled GEMM (layer-1 FFN: routing-critical, exact) ----------------
// MODE 0: fc1 (gather rows, GELU -> f32 a_buf)
// MODE 1: fc2 (compact rows, split-K=4, scal*(acc[+bias]) -> per-chunk compact buffer)
template <int MODE>
__launch_bounds__(256)
__global__ void gemm_k(const float* __restrict__ Abase, int ldA,
                       const float* __restrict__ Bbase,
                       const float* __restrict__ bias,
                       float* __restrict__ Cout,
                       const int* __restrict__ list,
                       const int* __restrict__ off,
                       const int* __restrict__ cnt,
                       const float* __restrict__ scal,
                       int N, int Kd) {
  const int e = blockIdx.z;
  int M = cnt[e];
  const int m0 = blockIdx.x * 128;
  if (m0 >= M) return;
  int nb = blockIdx.y, kc = 0;
  if constexpr (MODE == 1) { nb = blockIdx.y >> 2; kc = blockIdx.y & 3; }
  const int n0 = nb * 128;
  int roff = off[e];
  const float* Bp = Bbase + (size_t)e * (size_t)N * (size_t)Kd;
  const float* be = bias + (size_t)e * (size_t)N;
  const int kBeg = (MODE == 1) ? kc * (Kd >> 2) : 0;
  const int kEnd = (MODE == 1) ? kBeg + (Kd >> 2) : Kd;

  __shared__ float As[16][132];
  __shared__ float Bs[16][132];

  const int tid = threadIdx.x;
  const float* aptr[2];
  const float* bptr[2];
#pragma unroll
  for (int q = 0; q < 2; q++) {
    int s = tid + q * 256;
    int row = s >> 2, kq = (s & 3) * 4;
    int r = m0 + row;
    int rc = r < M ? r : M - 1;
    size_t asrc;
    if constexpr (MODE == 0) asrc = (size_t)list[roff + rc] * (size_t)ldA;
    else asrc = (size_t)(roff + rc) * (size_t)ldA;
    aptr[q] = Abase + asrc + kq;
    bptr[q] = Bp + (size_t)(n0 + row) * (size_t)Kd + kq;
  }

  float acc[8][8] = {};
  const int tx = tid & 15, ty = tid >> 4;

  for (int k0 = kBeg; k0 < kEnd; k0 += 16) {
#pragma unroll
    for (int q = 0; q < 2; q++) {
      int s = tid + q * 256;
      int row = s >> 2, kq = (s & 3) * 4;
      float4 va = *(const float4*)(aptr[q] + k0);
      float4 vb = *(const float4*)(bptr[q] + k0);
      As[kq + 0][row] = va.x; As[kq + 1][row] = va.y;
      As[kq + 2][row] = va.z; As[kq + 3][row] = va.w;
      Bs[kq + 0][row] = vb.x; Bs[kq + 1][row] = vb.y;
      Bs[kq + 2][row] = vb.z; Bs[kq + 3][row] = vb.w;
    }
    __syncthreads();
#pragma unroll
    for (int k = 0; k < 16; k++) {
      float a[8], b[8];
      *(float4*)&a[0] = *(const float4*)&As[k][ty * 8];
      *(float4*)&a[4] = *(const float4*)&As[k][ty * 8 + 4];
      *(float4*)&b[0] = *(const float4*)&Bs[k][tx * 8];
      *(float4*)&b[4] = *(const float4*)&Bs[k][tx * 8 + 4];
#pragma unroll
      for (int i = 0; i < 8; i++)
#pragma unroll
        for (int j = 0; j < 8; j++)
          acc[i][j] = fmaf(a[i], b[j], acc[i][j]);
    }
    __syncthreads();
  }

#pragma unroll
  for (int i = 0; i < 8; i++) {
    int gm = m0 + ty * 8 + i;
    if (gm >= M) continue;
    if constexpr (MODE == 0) {
      float* orow = Cout + (size_t)(roff + gm) * (size_t)N + n0 + tx * 8;
#pragma unroll
      for (int j = 0; j < 8; j++) {
        float x = acc[i][j] + be[n0 + tx * 8 + j];
        orow[j] = 0.5f * x * (1.f + erff(x * 0.70710678118654752f));
      }
    } else {
      float se = scal[e];
      float* orow = Cout + (size_t)kc * ((size_t)kR * kH) +
                    (size_t)(roff + gm) * (size_t)N + n0 + tx * 8;
      float4 o0, o1;
      float b0 = (kc == 0) ? be[n0 + tx * 8 + 0] : 0.f;
      float b1 = (kc == 0) ? be[n0 + tx * 8 + 1] : 0.f;
      float b2 = (kc == 0) ? be[n0 + tx * 8 + 2] : 0.f;
      float b3 = (kc == 0) ? be[n0 + tx * 8 + 3] : 0.f;
      float b4 = (kc == 0) ? be[n0 + tx * 8 + 4] : 0.f;
      float b5 = (kc == 0) ? be[n0 + tx * 8 + 5] : 0.f;
      float b6 = (kc == 0) ? be[n0 + tx * 8 + 6] : 0.f;
      float b7 = (kc == 0) ? be[n0 + tx * 8 + 7] : 0.f;
      o0.x = se * (acc[i][0] + b0); o0.y = se * (acc[i][1] + b1);
      o0.z = se * (acc[i][2] + b2); o0.w = se * (acc[i][3] + b3);
      o1.x = se * (acc[i][4] + b4); o1.y = se * (acc[i][5] + b5);
      o1.z = se * (acc[i][6] + b6); o1.w = se * (acc[i][7] + b7);
      *(float4*)&orow[0] = o0;
      *(float4*)&orow[4] = o1;
    }
  }
}

// ---------------- bf16 MFMA GEMM with in-register f32->bf16 staging ----------------
// 128x128 tile, BK=64, 256 threads = 4 waves (2x2), 16x16x32 bf16 MFMA.
// MODE 0: fc1-l2 (A rows via list gather, GELU -> f32 a_buf)
// MODE 1: fc2-l2 (A = compact a_buf, split-K=4, scal*(acc[+bias]) -> per-chunk compact)
// MODE 2: head  (dense, +bias -> f32 out)
template <int MODE>
__launch_bounds__(256)
__global__ void mgemm_k(const float* __restrict__ Abase, int ldA,
                        const float* __restrict__ Bbase,
                        const float* __restrict__ bias,
                        float* __restrict__ Cout,
                        const int* __restrict__ list,
                        const int* __restrict__ off,
                        const int* __restrict__ cnt,
                        const float* __restrict__ scal,
                        int N, int Kd) {
  const int e = (MODE == 2) ? 0 : blockIdx.z;
  int M;
  if constexpr (MODE == 2) M = kT; else M = cnt[e];
  const int m0 = blockIdx.x * 128;
  if (m0 >= M) return;
  int nb = blockIdx.y, kc = 0;
  if constexpr (MODE == 1) { nb = blockIdx.y >> 2; kc = blockIdx.y & 3; }
  const int n0 = nb * 128;
  int roff = 0;
  if constexpr (MODE != 2) roff = off[e];
  const float* Bp = Bbase + (size_t)e * (size_t)N * (size_t)Kd;
  const float* be = bias + (size_t)e * (size_t)N;
  const int kBeg = (MODE == 1) ? kc * (Kd >> 2) : 0;
  const int kEnd = (MODE == 1) ? kBeg + (Kd >> 2) : Kd;

  __shared__ unsigned short As[128 * 64];
  __shared__ unsigned short Bs[128 * 64];

  const int tid = threadIdx.x, w = tid >> 6, l = tid & 63;

  const float* asrc[4];
  const float* bsrc[4];
#pragma unroll
  for (int i = 0; i < 4; i++) {
    int r = w * 8 + i * 32 + (l >> 3);
    int gr = m0 + r; if (gr > M - 1) gr = M - 1;
    long grow;
    if constexpr (MODE == 0) grow = list[roff + gr];
    else if constexpr (MODE == 1) grow = roff + gr;
    else grow = gr;
    asrc[i] = Abase + grow * (long)ldA + (l & 7) * 8;
    bsrc[i] = Bp + (size_t)(n0 + r) * (size_t)Kd + (l & 7) * 8;
  }
  const int ldst = w * 512 + (l >> 3) * 64 + (l & 7) * 8;  // bf16-elem offset

  f32x4 acc[4][4] = {};
  const int wm = w >> 1, wn = w & 1;
  const int fr = l & 15, fk = (l >> 4) * 8;

  float4 ra[4][2], rb[4][2];

#define LOAD_TILE(K0)                                        \
  _Pragma("unroll") for (int i = 0; i < 4; i++) {            \
    ra[i][0] = *(const float4*)(asrc[i] + (K0));             \
    ra[i][1] = *(const float4*)(asrc[i] + (K0) + 4);         \
    rb[i][0] = *(const float4*)(bsrc[i] + (K0));             \
    rb[i][1] = *(const float4*)(bsrc[i] + (K0) + 4);         \
  }

  LOAD_TILE(kBeg);

  for (int k0 = kBeg; k0 < kEnd; k0 += 64) {
#pragma unroll
    for (int i = 0; i < 4; i++) {
      uint4 pa, pb;
      pa.x = cvtpk(ra[i][0].x, ra[i][0].y);
      pa.y = cvtpk(ra[i][0].z, ra[i][0].w);
      pa.z = cvtpk(ra[i][1].x, ra[i][1].y);
      pa.w = cvtpk(ra[i][1].z, ra[i][1].w);
      pb.x = cvtpk(rb[i][0].x, rb[i][0].y);
      pb.y = cvtpk(rb[i][0].z, rb[i][0].w);
      pb.z = cvtpk(rb[i][1].x, rb[i][1].y);
      pb.w = cvtpk(rb[i][1].z, rb[i][1].w);
      *(uint4*)(As + ldst + i * 2048) = pa;
      *(uint4*)(Bs + ldst + i * 2048) = pb;
    }
    __syncthreads();
    if (k0 + 64 < kEnd) LOAD_TILE(k0 + 64);  // prefetch; latency hides under MFMA
#pragma unroll
    for (int ks = 0; ks < 2; ks++) {
      bf16x8 af[4], bfr[4];
#pragma unroll
      for (int am = 0; am < 4; am++)
        af[am] = *(const bf16x8*)(As + (wm * 64 + am * 16 + fr) * 64 + ks * 32 + fk);
#pragma unroll
      for (int bn = 0; bn < 4; bn++)
        bfr[bn] = *(const bf16x8*)(Bs + (wn * 64 + bn * 16 + fr) * 64 + ks * 32 + fk);
#pragma unroll
      for (int am = 0; am < 4; am++)
#pragma unroll
        for (int bn = 0; bn < 4; bn++)
          acc[am][bn] = __builtin_amdgcn_mfma_f32_16x16x32_bf16(af[am], bfr[bn], acc[am][bn], 0, 0, 0);
    }
    __syncthreads();
  }
#undef LOAD_TILE

  // C/D layout: col = lane&15, row = (lane>>4)*4 + j  (m89/m91-verified)
  const int r0 = (l >> 4) * 4, cc = l & 15;
#pragma unroll
  for (int am = 0; am < 4; am++) {
#pragma unroll
    for (int bn = 0; bn < 4; bn++) {
      int gn = n0 + wn * 64 + bn * 16 + cc;
      float bv;
      if constexpr (MODE == 1) bv = (kc == 0) ? be[gn] : 0.f;
      else bv = be[gn];
#pragma unroll
      for (int j = 0; j < 4; j++) {
        int gm = m0 + wm * 64 + am * 16 + r0 + j;
        if (gm >= M) continue;
        float v = acc[am][bn][j] + bv;
        if constexpr (MODE == 0) {
          float g = 0.5f * v * (1.f + erff(v * 0.70710678118654752f));
          Cout[(size_t)(roff + gm) * (size_t)N + gn] = g;
        } else if constexpr (MODE == 1) {
          Cout[(size_t)kc * ((size_t)kR * kH) + (size_t)(roff + gm) * (size_t)N + gn] =
              scal[e] * v;
        } else {
          Cout[(size_t)gm * (size_t)N + gn] = v;
        }
      }
    }
  }
}

// ---------------- launch ----------------

extern "C" void kernel_launch(void* const* d_in, const int* in_sizes, int n_in,
                              void* d_out, int out_size, void* d_ws, size_t ws_size,
                              hipStream_t stream) {
  (void)in_sizes; (void)n_in; (void)out_size; (void)ws_size;
  const int* ids = (const int*)d_in[0];
  const float* emb = (const float*)d_in[1];
  const float* router_w = (const float*)d_in[2];
  const float* router_b = (const float*)d_in[3];
  const float* fc1_w = (const float*)d_in[4];
  const float* fc1_b = (const float*)d_in[5];
  const float* fc2_w = (const float*)d_in[6];
  const float* fc2_b = (const float*)d_in[7];
  const float* ln_g = (const float*)d_in[8];
  const float* ln_b = (const float*)d_in[9];
  const float* head_w = (const float*)d_in[10];
  const float* head_b = (const float*)d_in[11];
  float* out = (float*)d_out;

  // --- workspace layout (~17 MB) ---
  float* ws_f = (float*)d_ws;
  float* h       = ws_f;                          // kT*kH
  float* logits  = h + (size_t)kT * kH;           // kT*kE
  float* w_sum   = logits + (size_t)kT * kE;      // kE
  float* scal    = w_sum + kE;                    // kE
  float* aux     = scal + kE;                     // 1
  int* sel  = (int*)(aux + 1);                    // kT*2
  int* cnt  = sel + 2 * kT;                       // kE
  int* off  = cnt + kE;                           // kE
  int* fill = off + kE;                           // kE
  int* list = fill + kE;                          // kR
  int* pos  = list + kR;                          // kT*2

  // --- d_out scratch (head overwrites everything at the end) ---
  float* a_f32  = out;                            // kR*kI f32 (64 MB)
  float* c_comp = a_f32 + (size_t)kR * kI;        // kSK*kR*kH f32 (64 MB)

  hipMemsetAsync(aux, 0, sizeof(float), stream);
  gather_k<<<kT, 256, 0, stream>>>(ids, emb, h);

  for (int l = 0; l < kL; l++) {
    hipMemsetAsync(w_sum, 0, kE * sizeof(float), stream);
    hipMemsetAsync(cnt, 0, kE * sizeof(int), stream);
    router_k<<<kT, 256, 0, stream>>>(h, router_w + (size_t)l * kE * kH,
                                     router_b + (size_t)l * kE, logits);
    topk_k<<<kT / 256, 256, 0, stream>>>(logits, sel, w_sum, cnt);
    finalize_k<<<1, 64, 0, stream>>>(cnt, w_sum, scal, off, fill, aux);
    scatter_k<<<kT / 256, 256, 0, stream>>>(sel, off, fill, list, pos);

    if (l == 0) {
      // layer-1: exact f32 (its output feeds the layer-2 router)
      gemm_k<0><<<dim3(kT / 128, kI / 128, kE), 256, 0, stream>>>(
          h, kH, fc1_w + (size_t)l * kE * kI * kH, fc1_b + (size_t)l * kE * kI,
          a_f32, list, off, cnt, scal, kI, kH);
      gemm_k<1><<<dim3(kT / 128, (kH / 128) * kSK, kE), 256, 0, stream>>>(
          a_f32, kI, fc2_w + (size_t)l * kE * kH * kI, fc2_b + (size_t)l * kE * kH,
          c_comp, list, off, cnt, scal, kH, kI);
    } else {
      // layer-2: bf16 MFMA, f32 operands converted during staging
      mgemm_k<0><<<dim3(kT / 128, kI / 128, kE), 256, 0, stream>>>(
          h, kH, fc1_w + (size_t)l * kE * kI * kH, fc1_b + (size_t)l * kE * kI,
          a_f32, list, off, cnt, scal, kI, kH);
      mgemm_k<1><<<dim3(kT / 128, (kH / 128) * kSK, kE), 256, 0, stream>>>(
          a_f32, kI, fc2_w + (size_t)l * kE * kH * kI, fc2_b + (size_t)l * kE * kH,
          c_comp, list, off, cnt, scal, kH, kI);
    }

    combine_ln_k<<<kT, 256, 0, stream>>>(c_comp, pos, h,
                                         ln_g + (size_t)l * kH, ln_b + (size_t)l * kH);
  }

  // head: bf16 MFMA with f32 staging; reads h (ws) + head_w, writes all of d_out
  mgemm_k<2><<<dim3(kT / 128, kV / 128, 1), 256, 0, stream>>>(
      h, kH, head_w, head_b, out, nullptr, nullptr, nullptr, nullptr, kV, kH);

  aux_write_k<<<1, 1, 0, stream>>>(out, aux);
}